// Round 1
// baseline (2487.319 us; speedup 1.0000x reference)
//
#include <hip/hip_runtime.h>
#include <hip/hip_bf16.h>
#include <stdint.h>

typedef _Float16 f16;
typedef _Float16 f16x8 __attribute__((ext_vector_type(8)));
typedef float    f32x4 __attribute__((ext_vector_type(4)));

#define B_N 1024
#define T_N 128
#define U_N 256
#define G3  768    // 3U
#define NC  1024   // pre columns: [r | z | xh | msgE_h]
#define KC  512    // concat K: [inputs | em_sum]
#define M_N (B_N * T_N)

// ---------------- prep: build WcatT (f16, [1024][512]), bias (f32,1024), Uh16 (f16,[256][768]) ----------------
__global__ void k_prep(const float* __restrict__ Wx, const float* __restrict__ Uh,
                       const float* __restrict__ Ve, const float* __restrict__ bsrc,
                       f16* __restrict__ WcatT, float* __restrict__ bias, f16* __restrict__ Uh16)
{
  int idx = blockIdx.x * 256 + threadIdx.x;
  if (idx < NC * KC) {
    int n = idx >> 9, k = idx & 511;
    float v;
    if (n < 512)      v = (k < 256) ? Wx[k * G3 + n] : Ve[(k - 256) * G3 + n];
    else if (n < 768) v = (k < 256) ? Wx[k * G3 + n] : 0.f;
    else              v = (k < 256) ? 0.f : Ve[(k - 256) * G3 + (n - 256)];
    WcatT[n * KC + k] = (f16)v;
  }
  int i2 = idx - NC * KC;
  if (i2 >= 0 && i2 < U_N * G3) Uh16[i2] = (f16)Uh[i2];
  int i3 = idx - NC * KC - U_N * G3;
  if (i3 >= 0 && i3 < NC) bias[i3] = (i3 < G3) ? bsrc[i3] : 0.f;
}

// ---------------- build A (f16, [M][512]): [ f16(inputs) | f16(em_sum) ] ----------------
__global__ void k_build_a(const float* __restrict__ inp, const int* __restrict__ et,
                          const int* __restrict__ cmk, const float* __restrict__ emb,
                          f16* __restrict__ A)
{
  int m = blockIdx.x * 4 + (threadIdx.x >> 8);
  int u = threadIdx.x & 255;
  const int* e = et  + (size_t)m * 4;
  const int* c = cmk + (size_t)m * 4;
  float em = 0.f;
  #pragma unroll
  for (int r = 0; r < 4; ++r)
    if (c[r]) em += emb[e[r] * U_N + u];
  A[(size_t)m * KC + u]       = (f16)inp[(size_t)m * 256 + u];
  A[(size_t)m * KC + 256 + u] = (f16)em;
}

// ---------------- GEMM: C[M][1024] (f16) = A[M][512] @ WcatT^T + bias ----------------
// 128x128 tile, BK=32, 4 waves (2x2 of 64x64), 16x16x32 f16 MFMA, reg-staged LDS w/ XOR swizzle.
__global__ __launch_bounds__(256) void k_gemm(const f16* __restrict__ A,
                                              const f16* __restrict__ BT,   // [1024][512]
                                              const float* __restrict__ bias,
                                              f16* __restrict__ C)
{
  __shared__ f16 sA[128 * 32];
  __shared__ f16 sB[128 * 32];
  const int tid  = threadIdx.x;
  const int lane = tid & 63, wv = tid >> 6;
  const int wm = wv >> 1, wn = wv & 1;
  const int bid = blockIdx.x;
  const int m0 = (bid >> 3) * 128;
  const int n0 = (bid & 7)  * 128;

  f32x4 acc[4][4] = {};

  for (int kt = 0; kt < 16; ++kt) {
    const int k0 = kt * 32;
    #pragma unroll
    for (int is = 0; is < 2; ++is) {
      int t2  = is * 256 + tid;          // 16B chunk id, 512 per tile
      int row = t2 >> 2, c = t2 & 3;
      f16x8 va = *(const f16x8*)(A  + (size_t)(m0 + row) * KC + k0 + c * 8);
      *(f16x8*)(sA + row * 32 + ((c ^ (row & 3)) * 8)) = va;
      f16x8 vb = *(const f16x8*)(BT + (size_t)(n0 + row) * KC + k0 + c * 8);
      *(f16x8*)(sB + row * 32 + ((c ^ (row & 3)) * 8)) = vb;
    }
    __syncthreads();

    const int kb = lane >> 4;            // 0..3 (8-f16 chunk along K)
    f16x8 af[4], bf[4];
    #pragma unroll
    for (int i = 0; i < 4; ++i) {
      int ar = wm * 64 + i * 16 + (lane & 15);
      af[i] = *(const f16x8*)(sA + ar * 32 + ((kb ^ (ar & 3)) * 8));
      int br = wn * 64 + i * 16 + (lane & 15);
      bf[i] = *(const f16x8*)(sB + br * 32 + ((kb ^ (br & 3)) * 8));
    }
    #pragma unroll
    for (int i = 0; i < 4; ++i)
      #pragma unroll
      for (int j = 0; j < 4; ++j)
        acc[i][j] = __builtin_amdgcn_mfma_f32_16x16x32_f16(af[i], bf[j], acc[i][j], 0, 0, 0);
    __syncthreads();
  }

  #pragma unroll
  for (int i = 0; i < 4; ++i)
    #pragma unroll
    for (int j = 0; j < 4; ++j) {
      int col = n0 + wn * 64 + j * 16 + (lane & 15);
      float bv = bias[col];
      #pragma unroll
      for (int r = 0; r < 4; ++r) {
        int row = m0 + wm * 64 + i * 16 + (lane >> 4) * 4 + r;
        C[(size_t)row * NC + col] = (f16)(acc[i][j][r] + bv);
      }
    }
}

// ---------------- scan: 256 blocks x 512 threads, 4 batch rows per block ----------------
__global__ __launch_bounds__(512) void k_scan(
    const f16* __restrict__ pre,   // [B*T][1024] = [tot_r | tot_z | xh | msgE_h] (r/z include e@Ve + bias)
    const f16* __restrict__ Uh16,  // [256][768]
    const int* __restrict__ dep,   // [B][T][3]
    const int* __restrict__ cmk,   // [B][T][4]
    const int* __restrict__ msk,   // [B][T]
    float* __restrict__ H,         // [T][B][256]
    float* __restrict__ out)       // [B][256]
{
  __shared__ float s_f32[4][256];
  __shared__ float h_prev[4][256];
  __shared__ float accp[256][13];
  __shared__ float sc_cnt[4];
  __shared__ int   sc_m[4];

  const int tid  = threadIdx.x;
  const int u    = tid & 255, half = tid >> 8;
  const int b0   = blockIdx.x * 4;

  h_prev[half * 2][u]     = 0.f;
  h_prev[half * 2 + 1][u] = 0.f;
  __syncthreads();

  for (int t = 0; t < T_N; ++t) {
    // ---- phase 1: gather masked sum s (and per-row scalars) ----
    #pragma unroll
    for (int rr0 = 0; rr0 < 2; ++rr0) {
      const int rr = half * 2 + rr0;
      const int b  = b0 + rr;
      const int* dp = dep + ((size_t)b * T_N + t) * 3;
      const int* cp = cmk + ((size_t)b * T_N + t) * 4;
      float sv = cp[0] ? h_prev[rr][u] : 0.f;
      #pragma unroll
      for (int r = 0; r < 3; ++r) {
        int d = dp[r];
        if (cp[r + 1] && (d < t)) sv += H[((size_t)d * B_N + b) * 256 + u];
      }
      s_f32[rr][u] = sv;
      if (u == 0) {
        sc_cnt[rr] = (float)((cp[0] ? 1 : 0) + (cp[1] ? 1 : 0) + (cp[2] ? 1 : 0) + (cp[3] ? 1 : 0));
        sc_m[rr]   = msk[(size_t)b * T_N + t];
      }
    }
    __syncthreads();

    // ---- phase 2: msg = s @ Uh, u-split across the two halves ----
    float a0[4] = {0, 0, 0, 0}, a1[4] = {0, 0, 0, 0}, a2[4] = {0, 0, 0, 0};
    const int g  = u;
    const int j0 = half * 128;
    #pragma unroll 4
    for (int j = j0; j < j0 + 128; ++j) {
      const f16* up = Uh16 + (size_t)j * G3 + g;
      float ur  = (float)up[0];
      float uz  = (float)up[256];
      float uhh = (float)up[512];
      #pragma unroll
      for (int row = 0; row < 4; ++row) {
        float sp = s_f32[row][j];
        a0[row] = fmaf(sp, ur,  a0[row]);
        a1[row] = fmaf(sp, uz,  a1[row]);
        a2[row] = fmaf(sp, uhh, a2[row]);
      }
    }
    if (half == 1) {
      #pragma unroll
      for (int row = 0; row < 4; ++row) {
        accp[g][row * 3 + 0] = a0[row];
        accp[g][row * 3 + 1] = a1[row];
        accp[g][row * 3 + 2] = a2[row];
      }
    }
    __syncthreads();

    // ---- phase 3: gates + state update (half 0 only) ----
    if (half == 0) {
      #pragma unroll
      for (int row = 0; row < 4; ++row) {
        float mr = a0[row] + accp[g][row * 3 + 0];
        float mz = a1[row] + accp[g][row * 3 + 1];
        float mh = a2[row] + accp[g][row * 3 + 2];
        const f16* pb = pre + ((size_t)(b0 + row) * T_N + t) * NC;
        float tr = (float)pb[g]       + mr;
        float tz = (float)pb[g + 256] + mz;
        float xh = (float)pb[g + 512];
        float eh = (float)pb[g + 768];
        float rg = 1.f / (1.f + __expf(-tr));
        float zg = 1.f / (1.f + __expf(-tz));
        float hc = tanhf(xh + rg * (mh + eh));
        float hb = s_f32[row][g] / fmaxf(sc_cnt[row], 1.f);
        float hn = zg * hb + (1.f - zg) * hc;
        float ho = sc_m[row] ? hn : h_prev[row][g];
        h_prev[row][g] = ho;
        H[((size_t)t * B_N + (b0 + row)) * 256 + g] = ho;
        if (t == T_N - 1) out[(size_t)(b0 + row) * 256 + g] = sc_m[row] ? ho : 0.f;
      }
    }
    __syncthreads();
  }
}

extern "C" void kernel_launch(void* const* d_in, const int* in_sizes, int n_in,
                              void* d_out, int out_size, void* d_ws, size_t ws_size,
                              hipStream_t stream)
{
  const float* inputs = (const float*)d_in[0];
  // d_in[1] = input_lengths (unused)
  const int*   deps   = (const int*)d_in[2];
  const int*   et     = (const int*)d_in[3];
  const int*   msk    = (const int*)d_in[4];
  const int*   cmk    = (const int*)d_in[5];
  const float* Wx     = (const float*)d_in[6];
  const float* Uh     = (const float*)d_in[7];
  const float* Ve     = (const float*)d_in[8];
  const float* bb     = (const float*)d_in[9];
  const float* emb    = (const float*)d_in[10];
  float* out = (float*)d_out;

  char* ws = (char*)d_ws;
  // layout: A (f16, 128MB, aliased by H after GEMM) | pre (f16, 256MB) | WcatT | bias | Uh16
  f16*   A     = (f16*)ws;
  float* H     = (float*)ws;                       // alias of A (A dead after GEMM)
  f16*   pre   = (f16*)(ws + 134217728);
  f16*   WcatT = (f16*)(ws + 402653184);
  float* bias  = (float*)(ws + 403701760);
  f16*   Uh16  = (f16*)(ws + 403705856);
  // total ws needed: ~404.1 MB

  k_prep<<<dim3((NC * KC + U_N * G3 + NC + 255) / 256), dim3(256), 0, stream>>>(
      Wx, Uh, Ve, bb, WcatT, bias, Uh16);
  k_build_a<<<dim3(M_N / 4), dim3(1024), 0, stream>>>(inputs, et, cmk, emb, A);
  k_gemm<<<dim3((M_N / 128) * (NC / 128)), dim3(256), 0, stream>>>(A, WcatT, bias, pre);
  k_scan<<<dim3(B_N / 4), dim3(512), 0, stream>>>(pre, Uh16, deps, cmk, msk, H, out);
}

// Round 2
// 1293.850 us; speedup vs baseline: 1.9224x; 1.9224x over previous
//
#include <hip/hip_runtime.h>
#include <hip/hip_bf16.h>
#include <stdint.h>

typedef _Float16 f16;
typedef _Float16 f16x8 __attribute__((ext_vector_type(8)));
typedef _Float16 f16x4 __attribute__((ext_vector_type(4)));
typedef float    f32x4 __attribute__((ext_vector_type(4)));

#define B_N 1024
#define T_N 128
#define U_N 256
#define G3  768    // 3U
#define NC  1024   // pre columns, permuted: col' = u*4 + part, part in {r,z,xh,eh}
#define KC  512    // concat K: [inputs | em_sum]
#define M_N (B_N * T_N)
#define SFP  260   // f32 LDS row stride (word stride ≡ 4 mod 32 -> conflict-free)
#define S16P 264   // f16 LDS row stride (528B, ≡ 4 mod 32 words)

// ---------------- prep: WcatT (f16 [1024][512], permuted cols), bias' (f32 1024),
// ----------------       UhF (f16, MFMA-fragment-ordered, gate-interleaved cols) ----------------
__global__ void k_prep(const float* __restrict__ Wx, const float* __restrict__ Uh,
                       const float* __restrict__ Ve, const float* __restrict__ bsrc,
                       f16* __restrict__ WcatT, float* __restrict__ bias, f16* __restrict__ UhF)
{
  int idx = blockIdx.x * 256 + threadIdx.x;
  if (idx < NC * KC) {
    int np = idx >> 9, k = idx & 511;       // np = permuted col, k = 0..511
    int u = np >> 2, part = np & 3;
    float v;
    if (part == 0)      v = (k < 256) ? Wx[k * G3 + u]         : Ve[(k - 256) * G3 + u];
    else if (part == 1) v = (k < 256) ? Wx[k * G3 + 256 + u]   : Ve[(k - 256) * G3 + 256 + u];
    else if (part == 2) v = (k < 256) ? Wx[k * G3 + 512 + u]   : 0.f;
    else                v = (k < 256) ? 0.f                    : Ve[(k - 256) * G3 + 512 + u];
    WcatT[np * KC + k] = (f16)v;
    return;
  }
  int i2 = idx - NC * KC;
  if (i2 < U_N * G3) {
    // UhF flat: (((w*8 + kk)*6 + nt)*64 + lane)*8 + j
    int j = i2 & 7, lane = (i2 >> 3) & 63, fn = i2 >> 9;   // fn = (w*8+kk)*6+nt
    int nt = fn % 6, kkw = fn / 6;
    int kk = kkw & 7, w = kkw >> 3;
    int k = kk * 32 + (lane >> 4) * 8 + j;
    int npp = w * 96 + nt * 16 + (lane & 15);              // gate-interleaved col index
    int q = npp >> 4;
    int u = (q / 3) * 16 + (npp & 15), gate = q % 3;
    UhF[i2] = (f16)Uh[k * G3 + gate * 256 + u];
    return;
  }
  int i3 = i2 - U_N * G3;
  if (i3 < NC) {
    int u = i3 >> 2, part = i3 & 3;
    bias[i3] = (part < 3) ? bsrc[part * 256 + u] : 0.f;
  }
}

// ---------------- build A (f16, [M][512]): [ f16(inputs) | f16(em_sum) ] ----------------
__global__ void k_build_a(const float* __restrict__ inp, const int* __restrict__ et,
                          const int* __restrict__ cmk, const float* __restrict__ emb,
                          f16* __restrict__ A)
{
  int m = blockIdx.x * 4 + (threadIdx.x >> 8);
  int u = threadIdx.x & 255;
  const int* e = et  + (size_t)m * 4;
  const int* c = cmk + (size_t)m * 4;
  float em = 0.f;
  #pragma unroll
  for (int r = 0; r < 4; ++r)
    if (c[r]) em += emb[e[r] * U_N + u];
  A[(size_t)m * KC + u]       = (f16)inp[(size_t)m * 256 + u];
  A[(size_t)m * KC + 256 + u] = (f16)em;
}

// ---------------- GEMM: pre[M][1024] (f16) = A[M][512] @ WcatT^T + bias' ----------------
__global__ __launch_bounds__(256) void k_gemm(const f16* __restrict__ A,
                                              const f16* __restrict__ BT,   // [1024][512]
                                              const float* __restrict__ bias,
                                              f16* __restrict__ C)
{
  __shared__ f16 sA[128 * 32];
  __shared__ f16 sB[128 * 32];
  const int tid  = threadIdx.x;
  const int lane = tid & 63, wv = tid >> 6;
  const int wm = wv >> 1, wn = wv & 1;
  const int bid = blockIdx.x;
  const int m0 = (bid >> 3) * 128;
  const int n0 = (bid & 7)  * 128;

  f32x4 acc[4][4] = {};

  for (int kt = 0; kt < 16; ++kt) {
    const int k0 = kt * 32;
    #pragma unroll
    for (int is = 0; is < 2; ++is) {
      int t2  = is * 256 + tid;
      int row = t2 >> 2, c = t2 & 3;
      f16x8 va = *(const f16x8*)(A  + (size_t)(m0 + row) * KC + k0 + c * 8);
      *(f16x8*)(sA + row * 32 + ((c ^ (row & 3)) * 8)) = va;
      f16x8 vb = *(const f16x8*)(BT + (size_t)(n0 + row) * KC + k0 + c * 8);
      *(f16x8*)(sB + row * 32 + ((c ^ (row & 3)) * 8)) = vb;
    }
    __syncthreads();

    const int kb = lane >> 4;
    f16x8 af[4], bf[4];
    #pragma unroll
    for (int i = 0; i < 4; ++i) {
      int ar = wm * 64 + i * 16 + (lane & 15);
      af[i] = *(const f16x8*)(sA + ar * 32 + ((kb ^ (ar & 3)) * 8));
      int br = wn * 64 + i * 16 + (lane & 15);
      bf[i] = *(const f16x8*)(sB + br * 32 + ((kb ^ (br & 3)) * 8));
    }
    #pragma unroll
    for (int i = 0; i < 4; ++i)
      #pragma unroll
      for (int j = 0; j < 4; ++j)
        acc[i][j] = __builtin_amdgcn_mfma_f32_16x16x32_f16(af[i], bf[j], acc[i][j], 0, 0, 0);
    __syncthreads();
  }

  #pragma unroll
  for (int i = 0; i < 4; ++i)
    #pragma unroll
    for (int j = 0; j < 4; ++j) {
      int col = n0 + wn * 64 + j * 16 + (lane & 15);
      float bv = bias[col];
      #pragma unroll
      for (int r = 0; r < 4; ++r) {
        int row = m0 + wm * 64 + i * 16 + (lane >> 4) * 4 + r;
        C[(size_t)row * NC + col] = (f16)(acc[i][j][r] + bv);
      }
    }
}

// ---------------- scan: 64 blocks x 512 threads (8 waves), 16 batch rows per block ----------------
// wave w holds Uh fragment slice for u in [32w, 32w+32) (all 3 gates) in 192 VGPRs.
__global__ __launch_bounds__(512) void k_scan2(
    const f16* __restrict__ pre,   // [B*T][1024], col' = u*4 + {r,z,xh,eh}
    const f16* __restrict__ UhF,   // fragment-ordered
    const int* __restrict__ dep,   // [B][T][3]
    const int* __restrict__ cmk,   // [B][T][4]
    const int* __restrict__ msk,   // [B][T]
    float* __restrict__ H,         // [T][B][256]
    float* __restrict__ out)       // [B][256]
{
  __shared__ f16   s16[16 * S16P];
  __shared__ float sf [16 * SFP];
  __shared__ float hp [16 * SFP];
  __shared__ int   sidx[2][16][8];   // [d0 d1 d2 cm0 cm1 cm2 cm3 m]

  const int tid  = threadIdx.x;
  const int lane = tid & 63, w = tid >> 6;
  const int l15  = lane & 15, lhi = lane >> 4;
  const int b0   = blockIdx.x * 16;

  // Uh fragments -> registers (held for whole kernel)
  f16x8 uh[48];
  {
    const f16* ub = UhF + ((size_t)w * 48 * 64 + lane) * 8;
    #pragma unroll
    for (int i = 0; i < 48; ++i)
      uh[i] = *(const f16x8*)(ub + i * 512);
  }

  for (int i = tid; i < 16 * SFP; i += 512) hp[i] = 0.f;

  if (tid < 128) {
    int rr = tid >> 3, f = tid & 7, b = b0 + rr;
    int v;
    if (f < 3)      v = dep[((size_t)b * T_N) * 3 + f];
    else if (f < 7) v = cmk[((size_t)b * T_N) * 4 + (f - 3)];
    else            v = msk[(size_t)b * T_N];
    sidx[0][rr][f] = v;
  }
  __syncthreads();

  for (int t = 0; t < T_N; ++t) {
    // ---- gather: s = cm0*h_prev + sum_r cm_{r+1}*[dep_r < t]*H[dep_r] ----
    {
      int rr = tid >> 5, uo = (tid & 31) * 8;
      const int* ix = &sidx[t & 1][rr][0];
      int b = b0 + rr;
      f32x4 a0, a1;
      if (ix[3]) {
        a0 = *(const f32x4*)(hp + rr * SFP + uo);
        a1 = *(const f32x4*)(hp + rr * SFP + uo + 4);
      } else {
        a0 = (f32x4){0.f, 0.f, 0.f, 0.f};
        a1 = (f32x4){0.f, 0.f, 0.f, 0.f};
      }
      #pragma unroll
      for (int r = 0; r < 3; ++r) {
        int d = ix[r];
        if (ix[4 + r] && (d < t)) {
          const float* hs = H + ((size_t)d * B_N + b) * 256 + uo;
          a0 += *(const f32x4*)(hs);
          a1 += *(const f32x4*)(hs + 4);
        }
      }
      *(f32x4*)(sf + rr * SFP + uo)     = a0;
      *(f32x4*)(sf + rr * SFP + uo + 4) = a1;
      f16x8 h8;
      #pragma unroll
      for (int j = 0; j < 4; ++j) { h8[j] = (f16)a0[j]; h8[j + 4] = (f16)a1[j]; }
      *(f16x8*)(s16 + rr * S16P + uo) = h8;
    }
    __syncthreads();

    // ---- prefetch pre for this step (consumed in update, hidden under MFMA) ----
    f16x4 pf[2][4];
    #pragma unroll
    for (int r = 0; r < 4; ++r)
      #pragma unroll
      for (int ub2 = 0; ub2 < 2; ++ub2)
        pf[ub2][r] = *(const f16x4*)(pre + (((size_t)(b0 + lhi * 4 + r) * T_N + t) << 10)
                                         + w * 128 + ub2 * 64 + l15 * 4);

    // ---- MFMA: msg[16][96-slice] = s @ Uh ----
    f32x4 acc[6];
    #pragma unroll
    for (int i = 0; i < 6; ++i) acc[i] = (f32x4){0.f, 0.f, 0.f, 0.f};
    #pragma unroll
    for (int kk = 0; kk < 8; ++kk) {
      f16x8 a = *(const f16x8*)(s16 + l15 * S16P + kk * 32 + lhi * 8);
      #pragma unroll
      for (int nt = 0; nt < 6; ++nt)
        acc[nt] = __builtin_amdgcn_mfma_f32_16x16x32_f16(a, uh[kk * 6 + nt], acc[nt], 0, 0, 0);
    }

    // ---- prefetch next step's indices (hidden under update) ----
    if (tid < 128 && (t + 1) < T_N) {
      int rr = tid >> 3, f = tid & 7, b = b0 + rr;
      int v;
      if (f < 3)      v = dep[((size_t)b * T_N + (t + 1)) * 3 + f];
      else if (f < 7) v = cmk[((size_t)b * T_N + (t + 1)) * 4 + (f - 3)];
      else            v = msk[(size_t)b * T_N + (t + 1)];
      sidx[(t + 1) & 1][rr][f] = v;
    }

    // ---- gate + state update (all in-lane: lane owns (4 rows) x (2 u-values)) ----
    #pragma unroll
    for (int ub2 = 0; ub2 < 2; ++ub2) {
      #pragma unroll
      for (int r = 0; r < 4; ++r) {
        int row = lhi * 4 + r;
        int u   = w * 32 + ub2 * 16 + l15;
        float mr = acc[ub2 * 3 + 0][r];
        float mz = acc[ub2 * 3 + 1][r];
        float mh = acc[ub2 * 3 + 2][r];
        f16x4 p = pf[ub2][r];
        float tr = (float)p.x + mr;
        float tz = (float)p.y + mz;
        float xh = (float)p.z;
        float eh = (float)p.w;
        float rg = 1.f / (1.f + __expf(-tr));
        float zg = 1.f / (1.f + __expf(-tz));
        float hc = tanhf(xh + rg * (mh + eh));
        const int* ix = &sidx[t & 1][row][0];
        float cnt = (float)(ix[3] + ix[4] + ix[5] + ix[6]);
        float hb = sf[row * SFP + u] / fmaxf(cnt, 1.f);
        float hn = zg * hb + (1.f - zg) * hc;
        float ho = ix[7] ? hn : hp[row * SFP + u];
        hp[row * SFP + u] = ho;
        H[((size_t)t * B_N + (b0 + row)) * 256 + u] = ho;
        if (t == T_N - 1) out[(size_t)(b0 + row) * 256 + u] = ix[7] ? ho : 0.f;
      }
    }
    __syncthreads();
  }
}

extern "C" void kernel_launch(void* const* d_in, const int* in_sizes, int n_in,
                              void* d_out, int out_size, void* d_ws, size_t ws_size,
                              hipStream_t stream)
{
  const float* inputs = (const float*)d_in[0];
  const int*   deps   = (const int*)d_in[2];
  const int*   et     = (const int*)d_in[3];
  const int*   msk    = (const int*)d_in[4];
  const int*   cmk    = (const int*)d_in[5];
  const float* Wx     = (const float*)d_in[6];
  const float* Uh     = (const float*)d_in[7];
  const float* Ve     = (const float*)d_in[8];
  const float* bb     = (const float*)d_in[9];
  const float* emb    = (const float*)d_in[10];
  float* out = (float*)d_out;

  char* ws = (char*)d_ws;
  f16*   A     = (f16*)ws;                     // 128 MB
  float* H     = (float*)ws;                   // alias of A (A dead after GEMM)
  f16*   pre   = (f16*)(ws + 134217728);       // 256 MB
  f16*   WcatT = (f16*)(ws + 402653184);       // 1 MB
  float* bias  = (float*)(ws + 403701760);     // 4 KB
  f16*   UhF   = (f16*)(ws + 403705856);       // 384 KB

  int prep_n = NC * KC + U_N * G3 + NC;
  k_prep<<<dim3((prep_n + 255) / 256), dim3(256), 0, stream>>>(Wx, Uh, Ve, bb, WcatT, bias, UhF);
  k_build_a<<<dim3(M_N / 4), dim3(1024), 0, stream>>>(inputs, et, cmk, emb, A);
  k_gemm<<<dim3((M_N / 128) * (NC / 128)), dim3(256), 0, stream>>>(A, WcatT, bias, pre);
  k_scan2<<<dim3(B_N / 16), dim3(512), 0, stream>>>(pre, UhF, deps, cmk, msk, H, out);
}

// Round 3
// 1141.751 us; speedup vs baseline: 2.1785x; 1.1332x over previous
//
#include <hip/hip_runtime.h>
#include <hip/hip_bf16.h>
#include <stdint.h>

typedef _Float16 f16;
typedef _Float16 f16x8 __attribute__((ext_vector_type(8)));
typedef _Float16 f16x4 __attribute__((ext_vector_type(4)));
typedef float    f32x4 __attribute__((ext_vector_type(4)));

#define B_N 1024
#define T_N 128
#define U_N 256
#define G3  768    // 3U
#define NC  1024   // pre columns, permuted: col' = u*4 + part, part in {r,z,xh,eh}
#define KC  512    // concat K: [inputs | em_sum]
#define M_N (B_N * T_N)
#define S16P 264   // f16 LDS row stride (528B, word stride ≡ 4 mod 32 -> 2-way max)

__device__ __forceinline__ void glds16(const void* g, void* l) {
  __builtin_amdgcn_global_load_lds((const __attribute__((address_space(1))) unsigned int*)g,
                                   (__attribute__((address_space(3))) unsigned int*)l, 16, 0, 0);
}
__device__ __forceinline__ void glds4(const void* g, void* l) {
  __builtin_amdgcn_global_load_lds((const __attribute__((address_space(1))) unsigned int*)g,
                                   (__attribute__((address_space(3))) unsigned int*)l, 4, 0, 0);
}

// ---------------- prep: WcatT (f16 [1024][512], permuted cols), bias' (f32 1024),
// ----------------       UhF (f16, MFMA-fragment-ordered, gate-interleaved cols) ----------------
__global__ void k_prep(const float* __restrict__ Wx, const float* __restrict__ Uh,
                       const float* __restrict__ Ve, const float* __restrict__ bsrc,
                       f16* __restrict__ WcatT, float* __restrict__ bias, f16* __restrict__ UhF)
{
  int idx = blockIdx.x * 256 + threadIdx.x;
  if (idx < NC * KC) {
    int np = idx >> 9, k = idx & 511;
    int u = np >> 2, part = np & 3;
    float v;
    if (part == 0)      v = (k < 256) ? Wx[k * G3 + u]         : Ve[(k - 256) * G3 + u];
    else if (part == 1) v = (k < 256) ? Wx[k * G3 + 256 + u]   : Ve[(k - 256) * G3 + 256 + u];
    else if (part == 2) v = (k < 256) ? Wx[k * G3 + 512 + u]   : 0.f;
    else                v = (k < 256) ? 0.f                    : Ve[(k - 256) * G3 + 512 + u];
    WcatT[np * KC + k] = (f16)v;
    return;
  }
  int i2 = idx - NC * KC;
  if (i2 < U_N * G3) {
    int j = i2 & 7, lane = (i2 >> 3) & 63, fn = i2 >> 9;   // fn = (w*8+kk)*6+nt
    int nt = fn % 6, kkw = fn / 6;
    int kk = kkw & 7, w = kkw >> 3;
    int k = kk * 32 + (lane >> 4) * 8 + j;
    int npp = w * 96 + nt * 16 + (lane & 15);
    int q = npp >> 4;
    int u = (q / 3) * 16 + (npp & 15), gate = q % 3;
    UhF[i2] = (f16)Uh[k * G3 + gate * 256 + u];
    return;
  }
  int i3 = i2 - U_N * G3;
  if (i3 < NC) {
    int u = i3 >> 2, part = i3 & 3;
    bias[i3] = (part < 3) ? bsrc[part * 256 + u] : 0.f;
  }
}

// ---------------- build A (f16, [M][512]): [ f16(inputs) | f16(em_sum) ] ----------------
__global__ __launch_bounds__(256) void k_build_a(const float* __restrict__ inp, const int* __restrict__ et,
                          const int* __restrict__ cmk, const float* __restrict__ emb,
                          f16* __restrict__ A)
{
  int m  = blockIdx.x * 4 + (threadIdx.x >> 6);
  int u4 = (threadIdx.x & 63) * 4;
  const int* e = et  + (size_t)m * 4;
  const int* c = cmk + (size_t)m * 4;
  f32x4 em = {0.f, 0.f, 0.f, 0.f};
  #pragma unroll
  for (int r = 0; r < 4; ++r)
    if (c[r]) em += *(const f32x4*)(emb + e[r] * U_N + u4);
  f32x4 x = *(const f32x4*)(inp + (size_t)m * 256 + u4);
  f16x4 xa, ea;
  #pragma unroll
  for (int j = 0; j < 4; ++j) { xa[j] = (f16)x[j]; ea[j] = (f16)em[j]; }
  *(f16x4*)(A + (size_t)m * KC + u4)       = xa;
  *(f16x4*)(A + (size_t)m * KC + 256 + u4) = ea;
}

// ---------------- GEMM: pre[M][1024] (f16) = A[M][512] @ WcatT^T + bias' ----------------
__global__ __launch_bounds__(256) void k_gemm(const f16* __restrict__ A,
                                              const f16* __restrict__ BT,
                                              const float* __restrict__ bias,
                                              f16* __restrict__ C)
{
  __shared__ f16 sA[128 * 32];
  __shared__ f16 sB[128 * 32];
  const int tid  = threadIdx.x;
  const int lane = tid & 63, wv = tid >> 6;
  const int wm = wv >> 1, wn = wv & 1;
  // XCD-aware swizzle: 8192 blocks, each XCD gets 1024 consecutive work items
  // -> the 8 n-blocks sharing an A-panel land on the same XCD (L2 reuse of A).
  const int wg = (blockIdx.x & 7) * 1024 + (blockIdx.x >> 3);
  const int m0 = (wg >> 3) * 128;
  const int n0 = (wg & 7)  * 128;

  f32x4 acc[4][4] = {};

  for (int kt = 0; kt < 16; ++kt) {
    const int k0 = kt * 32;
    #pragma unroll
    for (int is = 0; is < 2; ++is) {
      int t2  = is * 256 + tid;
      int row = t2 >> 2, c = t2 & 3;
      f16x8 va = *(const f16x8*)(A  + (size_t)(m0 + row) * KC + k0 + c * 8);
      *(f16x8*)(sA + row * 32 + ((c ^ (row & 3)) * 8)) = va;
      f16x8 vb = *(const f16x8*)(BT + (size_t)(n0 + row) * KC + k0 + c * 8);
      *(f16x8*)(sB + row * 32 + ((c ^ (row & 3)) * 8)) = vb;
    }
    __syncthreads();

    const int kb = lane >> 4;
    f16x8 af[4], bf[4];
    #pragma unroll
    for (int i = 0; i < 4; ++i) {
      int ar = wm * 64 + i * 16 + (lane & 15);
      af[i] = *(const f16x8*)(sA + ar * 32 + ((kb ^ (ar & 3)) * 8));
      int br = wn * 64 + i * 16 + (lane & 15);
      bf[i] = *(const f16x8*)(sB + br * 32 + ((kb ^ (br & 3)) * 8));
    }
    #pragma unroll
    for (int i = 0; i < 4; ++i)
      #pragma unroll
      for (int j = 0; j < 4; ++j)
        acc[i][j] = __builtin_amdgcn_mfma_f32_16x16x32_f16(af[i], bf[j], acc[i][j], 0, 0, 0);
    __syncthreads();
  }

  #pragma unroll
  for (int i = 0; i < 4; ++i)
    #pragma unroll
    for (int j = 0; j < 4; ++j) {
      int col = n0 + wn * 64 + j * 16 + (lane & 15);
      float bv = bias[col];
      #pragma unroll
      for (int r = 0; r < 4; ++r) {
        int row = m0 + wm * 64 + i * 16 + (lane >> 4) * 4 + r;
        C[(size_t)row * NC + col] = (f16)(acc[i][j][r] + bv);
      }
    }
}

// ---------------- scan: 64 blocks x 512 threads (8 waves), 16 batch rows per block ----------------
// Per-step pipeline: prefetch dep-H (t+1) + sidx (t+2) via global_load_lds, hidden under MFMA/update.
// sidx fields: [cm0 cm1 cm2 cm3 d0 d1 d2 m]
__global__ __launch_bounds__(512, 2) void k_scan3(
    const f16* __restrict__ pre,   // [B*T][1024], col' = u*4 + {r,z,xh,eh}
    const f16* __restrict__ UhF,
    const int* __restrict__ dep,   // [B][T][3]
    const int* __restrict__ cmk,   // [B][T][4]
    const int* __restrict__ msk,   // [B][T]
    f16* __restrict__ H16,         // [T][B][256] f16
    float* __restrict__ out)       // [B][256]
{
  __shared__ __align__(16) f16   s16[16 * S16P];   // 8448 B
  __shared__ __align__(16) float hp [16 * 256];    // 16384 B
  __shared__ __align__(16) f16   dbuf[48 * 256];   // 24576 B (16 rows x 3 deps x 256 u)
  __shared__ __align__(16) int   sidx[3][16][8];   // 1536 B

  const int tid  = threadIdx.x;
  const int lane = tid & 63, w = tid >> 6;
  const int l15  = lane & 15, lhi = lane >> 4;
  const int b0   = blockIdx.x * 16;

  // Uh fragments -> registers (held for whole kernel; AGPR-eligible as MFMA B operands)
  f16x8 uh[48];
  {
    const f16* ub = UhF + ((size_t)w * 48 * 64 + lane) * 8;
    #pragma unroll
    for (int i = 0; i < 48; ++i) uh[i] = *(const f16x8*)(ub + i * 512);
  }

  for (int i = tid; i < 16 * 256; i += 512) hp[i] = 0.f;
  for (int i = tid; i < 48 * 128; i += 512) ((int*)dbuf)[i] = 0;

  // prologue: sidx for t=0 and t=1
  if (tid < 256) {
    int tt = tid >> 7;
    int f = tid & 7, rr = (tid >> 3) & 15, b = b0 + rr;
    int v;
    if (f < 4)      v = cmk[((size_t)b * T_N + tt) * 4 + f];
    else if (f < 7) v = dep[((size_t)b * T_N + tt) * 3 + (f - 4)];
    else            v = msk[(size_t)b * T_N + tt];
    sidx[tt][rr][f] = v;
  }
  __syncthreads();

  // per-thread invariant base for pre loads
  const f16* pbase = pre + ((size_t)(b0 + lhi * 4) * T_N) * NC + w * 128 + l15 * 4;

  for (int t = 0; t < T_N; ++t) {
    const int sl  = t % 3;
    const int sl1 = (t + 1) % 3;
    const int sl2 = (t + 2) % 3;

    // ---------------- phase A: combine gather, write s16, store H16[t-1] ----------------
    {
      const int rr = tid >> 5, uo = (tid & 31) * 8;
      const int* six = &sidx[sl][rr][0];
      int4 cmv = *(const int4*)(six);       // cm0..cm3
      int4 ddv = *(const int4*)(six + 4);   // d0 d1 d2 m
      f32x4 hv0 = *(const f32x4*)(hp + rr * 256 + uo);
      f32x4 hv1 = *(const f32x4*)(hp + rr * 256 + uo + 4);

      if (t > 0) {   // coalesced f16 store of h[t-1]
        f16x8 h8;
        #pragma unroll
        for (int j = 0; j < 4; ++j) { h8[j] = (f16)hv0[j]; h8[j + 4] = (f16)hv1[j]; }
        *(f16x8*)(H16 + ((size_t)(t - 1) * B_N + b0 + rr) * 256 + uo) = h8;
      }

      f32x4 a0 = {0.f,0.f,0.f,0.f}, a1 = {0.f,0.f,0.f,0.f};
      if (cmv.x) { a0 = hv0; a1 = hv1; }
      int dd[3] = {ddv.x, ddv.y, ddv.z};
      int cc[3] = {cmv.y, cmv.z, cmv.w};
      #pragma unroll
      for (int r = 0; r < 3; ++r) {
        f16x8 dv = *(const f16x8*)(dbuf + (rr * 3 + r) * 256 + uo);
        bool gb  = cc[r] && (dd[r] <= t - 2);   // prefetched global H
        bool hb_ = cc[r] && (dd[r] == t - 1);   // most recent h == hp
        #pragma unroll
        for (int j = 0; j < 4; ++j) {
          float v0 = gb ? (float)dv[j]     : (hb_ ? hv0[j] : 0.f);
          float v1 = gb ? (float)dv[j + 4] : (hb_ ? hv1[j] : 0.f);
          a0[j] += v0; a1[j] += v1;
        }
      }
      f16x8 s8;
      #pragma unroll
      for (int j = 0; j < 4; ++j) { s8[j] = (f16)a0[j]; s8[j + 4] = (f16)a1[j]; }
      *(f16x8*)(s16 + rr * S16P + uo) = s8;
    }
    __syncthreads();

    // ---------------- phase B ----------------
    // (a) prefetch dep-H rows for step t+1 (d <= t-1 valid; others garbage, selected away)
    if (t + 1 < T_N) {
      #pragma unroll
      for (int i = 0; i < 3; ++i) {
        int c  = 6 * w + 2 * i + (lane >> 5);
        int rr = c / 3, r = c % 3;
        int d  = sidx[sl1][rr][4 + r];
        const f16* src = H16 + ((size_t)d * B_N + (b0 + rr)) * 256 + (lane & 31) * 8;
        glds16(src, dbuf + (6 * w + 2 * i) * 256);
      }
    }
    // (b) prefetch sidx for t+2
    if (w < 2 && t + 2 < T_N) {
      int f0 = w * 64 + lane;
      int rr = f0 >> 3, f = f0 & 7, b = b0 + rr;
      const int* src;
      if (f < 4)      src = cmk + ((size_t)b * T_N + (t + 2)) * 4 + f;
      else if (f < 7) src = dep + ((size_t)b * T_N + (t + 2)) * 3 + (f - 4);
      else            src = msk + (size_t)b * T_N + (t + 2);
      glds4(src, (int*)&sidx[sl2][0][0] + w * 64);
    }
    // (c) pre loads for this step (consumed after MFMA)
    f16x4 pf[2][4];
    #pragma unroll
    for (int r = 0; r < 4; ++r)
      #pragma unroll
      for (int ub2 = 0; ub2 < 2; ++ub2)
        pf[ub2][r] = *(const f16x4*)(pbase + ((size_t)r * T_N + t) * NC + ub2 * 64);

    // (d) MFMA: msg[16][96-slice] = s @ Uh
    f32x4 acc[6];
    #pragma unroll
    for (int i = 0; i < 6; ++i) acc[i] = (f32x4){0.f, 0.f, 0.f, 0.f};
    #pragma unroll
    for (int kk = 0; kk < 8; ++kk) {
      f16x8 a = *(const f16x8*)(s16 + l15 * S16P + kk * 32 + lhi * 8);
      #pragma unroll
      for (int nt = 0; nt < 6; ++nt)
        acc[nt] = __builtin_amdgcn_mfma_f32_16x16x32_f16(a, uh[kk * 6 + nt], acc[nt], 0, 0, 0);
    }

    // (e) gate + state update (lane owns 4 rows x 2 u)
    #pragma unroll
    for (int r = 0; r < 4; ++r) {
      int row = lhi * 4 + r;
      int4 cmv = *(const int4*)(&sidx[sl][row][0]);
      int  mfl = sidx[sl][row][7];
      float cnt  = (float)(cmv.x + cmv.y + cmv.z + cmv.w);
      float rcnt = __builtin_amdgcn_rcpf(fmaxf(cnt, 1.f));
      #pragma unroll
      for (int ub2 = 0; ub2 < 2; ++ub2) {
        int u = w * 32 + ub2 * 16 + l15;
        float mr = acc[ub2 * 3 + 0][r];
        float mz = acc[ub2 * 3 + 1][r];
        float mh = acc[ub2 * 3 + 2][r];
        f16x4 p = pf[ub2][r];
        float tr = (float)p.x + mr;
        float tz = (float)p.y + mz;
        float hx = (float)p.z;
        float he = (float)p.w;
        float rg = __builtin_amdgcn_rcpf(1.f + __expf(-tr));
        float zg = __builtin_amdgcn_rcpf(1.f + __expf(-tz));
        float aa = hx + rg * (mh + he);
        float hc = 2.f * __builtin_amdgcn_rcpf(1.f + __expf(-2.f * aa)) - 1.f;
        float sv = (float)s16[row * S16P + u];
        float hb = sv * rcnt;
        float hn = zg * hb + (1.f - zg) * hc;
        float ho = mfl ? hn : hp[row * 256 + u];
        hp[row * 256 + u] = ho;
      }
    }
    __syncthreads();
  }

  // epilogue: out = m[T-1] ? h_last : 0
  {
    const int rr = tid >> 5, uo = (tid & 31) * 8;
    int m = sidx[(T_N - 1) % 3][rr][7];
    f32x4 o0, o1;
    #pragma unroll
    for (int j = 0; j < 4; ++j) {
      o0[j] = m ? hp[rr * 256 + uo + j]     : 0.f;
      o1[j] = m ? hp[rr * 256 + uo + 4 + j] : 0.f;
    }
    *(f32x4*)(out + (size_t)(b0 + rr) * 256 + uo)     = o0;
    *(f32x4*)(out + (size_t)(b0 + rr) * 256 + uo + 4) = o1;
  }
}

extern "C" void kernel_launch(void* const* d_in, const int* in_sizes, int n_in,
                              void* d_out, int out_size, void* d_ws, size_t ws_size,
                              hipStream_t stream)
{
  const float* inputs = (const float*)d_in[0];
  const int*   deps   = (const int*)d_in[2];
  const int*   et     = (const int*)d_in[3];
  const int*   msk    = (const int*)d_in[4];
  const int*   cmk    = (const int*)d_in[5];
  const float* Wx     = (const float*)d_in[6];
  const float* Uh     = (const float*)d_in[7];
  const float* Ve     = (const float*)d_in[8];
  const float* bb     = (const float*)d_in[9];
  const float* emb    = (const float*)d_in[10];
  float* out = (float*)d_out;

  char* ws = (char*)d_ws;
  f16*   A     = (f16*)ws;                     // 128 MB (A dead after GEMM)
  f16*   H16   = (f16*)ws;                     // 64 MB alias of A
  f16*   pre   = (f16*)(ws + 134217728);       // 256 MB
  f16*   WcatT = (f16*)(ws + 402653184);       // 1 MB
  float* bias  = (float*)(ws + 403701760);     // 4 KB
  f16*   UhF   = (f16*)(ws + 403705856);       // 384 KB

  int prep_n = NC * KC + U_N * G3 + NC;
  k_prep<<<dim3((prep_n + 255) / 256), dim3(256), 0, stream>>>(Wx, Uh, Ve, bb, WcatT, bias, UhF);
  k_build_a<<<dim3(M_N / 4), dim3(256), 0, stream>>>(inputs, et, cmk, emb, A);
  k_gemm<<<dim3((M_N / 128) * (NC / 128)), dim3(256), 0, stream>>>(A, WcatT, bias, pre);
  k_scan3<<<dim3(B_N / 16), dim3(512), 0, stream>>>(pre, UhF, deps, cmk, msk, H16, out);
}

// Round 4
// 579.587 us; speedup vs baseline: 4.2915x; 1.9699x over previous
//
#include <hip/hip_runtime.h>
#include <hip/hip_bf16.h>
#include <stdint.h>

typedef _Float16 f16;
typedef _Float16 f16x8 __attribute__((ext_vector_type(8)));
typedef _Float16 f16x4 __attribute__((ext_vector_type(4)));
typedef float    f32x4 __attribute__((ext_vector_type(4)));

#define B_N 1024
#define T_N 128
#define U_N 256
#define G3  768    // 3U
#define NC  1024   // pre columns, permuted: col' = u*4 + part, part in {r,z,xh,eh}
#define KC  512    // concat K: [inputs | em_sum]
#define M_N (B_N * T_N)
#define S16P 264   // f16 LDS row stride

__device__ __forceinline__ void glds16(const void* g, void* l) {
  __builtin_amdgcn_global_load_lds((const __attribute__((address_space(1))) unsigned int*)g,
                                   (__attribute__((address_space(3))) unsigned int*)l, 16, 0, 0);
}
__device__ __forceinline__ void glds4(const void* g, void* l) {
  __builtin_amdgcn_global_load_lds((const __attribute__((address_space(1))) unsigned int*)g,
                                   (__attribute__((address_space(3))) unsigned int*)l, 4, 0, 0);
}

// ---------------- prep ----------------
__global__ void k_prep(const float* __restrict__ Wx, const float* __restrict__ Uh,
                       const float* __restrict__ Ve, const float* __restrict__ bsrc,
                       f16* __restrict__ WcatT, float* __restrict__ bias, f16* __restrict__ UhF)
{
  int idx = blockIdx.x * 256 + threadIdx.x;
  if (idx < NC * KC) {
    int np = idx >> 9, k = idx & 511;
    int u = np >> 2, part = np & 3;
    float v;
    if (part == 0)      v = (k < 256) ? Wx[k * G3 + u]         : Ve[(k - 256) * G3 + u];
    else if (part == 1) v = (k < 256) ? Wx[k * G3 + 256 + u]   : Ve[(k - 256) * G3 + 256 + u];
    else if (part == 2) v = (k < 256) ? Wx[k * G3 + 512 + u]   : 0.f;
    else                v = (k < 256) ? 0.f                    : Ve[(k - 256) * G3 + 512 + u];
    WcatT[np * KC + k] = (f16)v;
    return;
  }
  int i2 = idx - NC * KC;
  if (i2 < U_N * G3) {
    int j = i2 & 7, lane = (i2 >> 3) & 63, fn = i2 >> 9;   // fn = (w*8+kk)*6+nt
    int nt = fn % 6, kkw = fn / 6;
    int kk = kkw & 7, w = kkw >> 3;
    int k = kk * 32 + (lane >> 4) * 8 + j;
    int npp = w * 96 + nt * 16 + (lane & 15);
    int q = npp >> 4;
    int u = (q / 3) * 16 + (npp & 15), gate = q % 3;
    UhF[i2] = (f16)Uh[k * G3 + gate * 256 + u];
    return;
  }
  int i3 = i2 - U_N * G3;
  if (i3 < NC) {
    int u = i3 >> 2, part = i3 & 3;
    bias[i3] = (part < 3) ? bsrc[part * 256 + u] : 0.f;
  }
}

// ---------------- build A ----------------
__global__ __launch_bounds__(256) void k_build_a(const float* __restrict__ inp, const int* __restrict__ et,
                          const int* __restrict__ cmk, const float* __restrict__ emb,
                          f16* __restrict__ A)
{
  int m  = blockIdx.x * 4 + (threadIdx.x >> 6);
  int u4 = (threadIdx.x & 63) * 4;
  const int* e = et  + (size_t)m * 4;
  const int* c = cmk + (size_t)m * 4;
  f32x4 em = {0.f, 0.f, 0.f, 0.f};
  #pragma unroll
  for (int r = 0; r < 4; ++r)
    if (c[r]) em += *(const f32x4*)(emb + e[r] * U_N + u4);
  f32x4 x = *(const f32x4*)(inp + (size_t)m * 256 + u4);
  f16x4 xa, ea;
  #pragma unroll
  for (int j = 0; j < 4; ++j) { xa[j] = (f16)x[j]; ea[j] = (f16)em[j]; }
  *(f16x4*)(A + (size_t)m * KC + u4)       = xa;
  *(f16x4*)(A + (size_t)m * KC + 256 + u4) = ea;
}

// ---------------- GEMM ----------------
__global__ __launch_bounds__(256) void k_gemm(const f16* __restrict__ A,
                                              const f16* __restrict__ BT,
                                              const float* __restrict__ bias,
                                              f16* __restrict__ C)
{
  __shared__ f16 sA[128 * 32];
  __shared__ f16 sB[128 * 32];
  const int tid  = threadIdx.x;
  const int lane = tid & 63, wv = tid >> 6;
  const int wm = wv >> 1, wn = wv & 1;
  const int wg = (blockIdx.x & 7) * 1024 + (blockIdx.x >> 3);
  const int m0 = (wg >> 3) * 128;
  const int n0 = (wg & 7)  * 128;

  f32x4 acc[4][4] = {};

  for (int kt = 0; kt < 16; ++kt) {
    const int k0 = kt * 32;
    #pragma unroll
    for (int is = 0; is < 2; ++is) {
      int t2  = is * 256 + tid;
      int row = t2 >> 2, c = t2 & 3;
      f16x8 va = *(const f16x8*)(A  + (size_t)(m0 + row) * KC + k0 + c * 8);
      *(f16x8*)(sA + row * 32 + ((c ^ (row & 3)) * 8)) = va;
      f16x8 vb = *(const f16x8*)(BT + (size_t)(n0 + row) * KC + k0 + c * 8);
      *(f16x8*)(sB + row * 32 + ((c ^ (row & 3)) * 8)) = vb;
    }
    __syncthreads();

    const int kb = lane >> 4;
    f16x8 af[4], bf[4];
    #pragma unroll
    for (int i = 0; i < 4; ++i) {
      int ar = wm * 64 + i * 16 + (lane & 15);
      af[i] = *(const f16x8*)(sA + ar * 32 + ((kb ^ (ar & 3)) * 8));
      int br = wn * 64 + i * 16 + (lane & 15);
      bf[i] = *(const f16x8*)(sB + br * 32 + ((kb ^ (br & 3)) * 8));
    }
    #pragma unroll
    for (int i = 0; i < 4; ++i)
      #pragma unroll
      for (int j = 0; j < 4; ++j)
        acc[i][j] = __builtin_amdgcn_mfma_f32_16x16x32_f16(af[i], bf[j], acc[i][j], 0, 0, 0);
    __syncthreads();
  }

  #pragma unroll
  for (int i = 0; i < 4; ++i)
    #pragma unroll
    for (int j = 0; j < 4; ++j) {
      int col = n0 + wn * 64 + j * 16 + (lane & 15);
      float bv = bias[col];
      #pragma unroll
      for (int r = 0; r < 4; ++r) {
        int row = m0 + wm * 64 + i * 16 + (lane >> 4) * 4 + r;
        C[(size_t)row * NC + col] = (f16)(acc[i][j][r] + bv);
      }
    }
}

// ---------------- scan: 256 blocks x 512 threads, 4 batch rows per block ----------------
// Counted-vmcnt pipeline: exactly 3 VMEM ops per wave per step.
//  op1: waves 0-5 glds16 dep-H for t+1 | waves 6-7 store H16[t-1]
//  op2: all waves glds16 pre row t+2
//  op3: all waves glds4 sidx fields for t+3 (redundant copies, benign)
// Waits: vmcnt(2) at phase A (dep buffer ready + own store drained); vmcnt(7) before update (pre ready).
// LDS h-ring (2 slots) covers deps d in {t-1, t-2}; global H16 only serves d <= t-3.
__global__ __launch_bounds__(512, 2) void k_scan4(
    const f16* __restrict__ pre,   // [B*T][1024], col' = u*4 + {r,z,xh,eh}
    const f16* __restrict__ UhF,
    const int* __restrict__ dep,   // [B][T][3]
    const int* __restrict__ cmk,   // [B][T][4]
    const int* __restrict__ msk,   // [B][T]
    f16* __restrict__ H16,         // [T+1][B][256] f16 (row T = scratch)
    float* __restrict__ out)       // [B][256]
{
  __shared__ __align__(16) f16 s16[16 * S16P];     // 8448 B (only rows 0,4,8,12 valid)
  __shared__ __align__(16) f16 hring[2][1024];     // 4096 B: h[t-1], h[t-2]
  __shared__ __align__(16) f16 dbuf[2][3072];      // 12288 B: 4 rows x 3 deps x 256
  __shared__ __align__(16) f16 spre[3][4096];      // 24576 B: pre rows, 3-deep
  __shared__ __align__(16) int sidxl[4][64];       // 1024 B: [cm0..3 d0..2 m] x 4 rows (+pad)
  __shared__ __align__(16) int dpad[64];           // dummy glds target

  const int tid  = threadIdx.x;
  const int lane = tid & 63, w = tid >> 6;
  const int l15  = lane & 15, lhi = lane >> 4;
  const int b0   = blockIdx.x * 4;

  // Uh fragments -> registers (held for whole kernel)
  f16x8 uh[48];
  {
    const f16* ub = UhF + ((size_t)w * 48 * 64 + lane) * 8;
    #pragma unroll
    for (int i = 0; i < 48; ++i) uh[i] = *(const f16x8*)(ub + i * 512);
  }

  ((int*)hring)[tid]       = 0;
  ((int*)hring)[tid + 512] = 0;

  // preload sidx for t = 0,1,2
  if (tid < 96) {
    int tt = tid >> 5, ll2 = tid & 31, rr = ll2 >> 3, f = ll2 & 7;
    size_t b = b0 + rr;
    int v;
    if (f < 4)      v = cmk[(b * T_N + tt) * 4 + f];
    else if (f < 7) v = dep[(b * T_N + tt) * 3 + (f - 4)];
    else            v = msk[b * T_N + tt];
    sidxl[tt][rr * 8 + f] = v;
  }
  __syncthreads();   // full drain once (also drains uh loads) — prologue only

  // per-thread invariant bases
  const f16* spre_src = pre + ((size_t)(b0 + (w >> 1)) * T_N) * 1024 + (w & 1) * 512 + lane * 8;
  const int  ll = lane & 31;
  const int  srr = ll >> 3, sf = ll & 7;
  const size_t sb = b0 + srr;
  const int* sidx_base;
  int sidx_stride;
  if (sf < 4)      { sidx_base = cmk + sb * T_N * 4 + sf;       sidx_stride = 4; }
  else if (sf < 7) { sidx_base = dep + sb * T_N * 3 + (sf - 4); sidx_stride = 3; }
  else             { sidx_base = msk + sb * T_N;                sidx_stride = 1; }
  const int dq  = 2 * w + (lane >> 5);        // waves 0-5: dep-pair id 0..11
  const int drr = dq / 3, drm = dq - drr * 3;
  const f16* dsrc_base = H16 + (size_t)(b0 + drr) * 256 + (lane & 31) * 8;
  const int strr = ((w - 6) * 64 + lane) >> 5;          // waves 6-7: store row
  const int stuo = (((w - 6) * 64 + lane) & 31) * 8;

  // prologue issues: spre rows 0,1 + 3 dummies  (5 ops/wave)
  #pragma unroll
  for (int pr = 0; pr < 2; ++pr)
    glds16(spre_src + (size_t)pr * 1024, &spre[pr][w * 512]);
  #pragma unroll
  for (int i = 0; i < 3; ++i)
    glds4(msk, &dpad[0]);

  for (int t = 0; t < T_N; ++t) {
    // ---- phase A ----
    asm volatile("s_waitcnt vmcnt(2)" ::: "memory");
    __builtin_amdgcn_sched_barrier(0);

    if (tid < 128) {
      const int rr = tid >> 5, uo = (tid & 31) * 8;
      const int* six = &sidxl[t & 3][rr * 8];
      int cm0 = six[0];
      int cms0 = six[1], cms1 = six[2], cms2 = six[3];
      int dd0 = six[4],  dd1 = six[5],  dd2 = six[6];
      f16x8 hprev = *(const f16x8*)&hring[(t + 1) & 1][rr * 256 + uo];  // h[t-1]
      f16x8 hold  = *(const f16x8*)&hring[t & 1][rr * 256 + uo];        // h[t-2]
      f32x4 a0 = {0.f,0.f,0.f,0.f}, a1 = {0.f,0.f,0.f,0.f};
      if (cm0) {
        #pragma unroll
        for (int j = 0; j < 4; ++j) { a0[j] += (float)hprev[j]; a1[j] += (float)hprev[j + 4]; }
      }
      int cma[3] = {cms0, cms1, cms2};
      int dda[3] = {dd0, dd1, dd2};
      #pragma unroll
      for (int r = 0; r < 3; ++r) {
        f16x8 dv = *(const f16x8*)&dbuf[t & 1][(rr * 3 + r) * 256 + uo];
        int d = dda[r];
        f16x8 src = (d == t - 1) ? hprev : ((d == t - 2) ? hold : dv);
        if (cma[r] && (d < t)) {
          #pragma unroll
          for (int j = 0; j < 4; ++j) { a0[j] += (float)src[j]; a1[j] += (float)src[j + 4]; }
        }
      }
      f16x8 s8;
      #pragma unroll
      for (int j = 0; j < 4; ++j) { s8[j] = (f16)a0[j]; s8[j + 4] = (f16)a1[j]; }
      *(f16x8*)&s16[(rr * 4) * S16P + uo] = s8;
    }
    asm volatile("s_waitcnt lgkmcnt(0)" ::: "memory");
    __builtin_amdgcn_s_barrier();
    __builtin_amdgcn_sched_barrier(0);

    // ---- phase B: op1 ----
    if (w < 6) {
      int d = sidxl[(t + 1) & 3][drr * 8 + 4 + drm];
      glds16(dsrc_base + (size_t)d * (B_N * 256), &dbuf[(t + 1) & 1][w * 512]);
    } else {
      f16x8 hv = *(const f16x8*)&hring[(t + 1) & 1][strr * 256 + stuo];
      int tt = (t == 0) ? T_N : (t - 1);
      *(f16x8*)(H16 + ((size_t)tt * B_N + b0 + strr) * 256 + stuo) = hv;
    }
    __builtin_amdgcn_sched_barrier(0);
    // op2: pre row t+2
    {
      int tt2 = (t + 2 < T_N) ? (t + 2) : (T_N - 1);
      glds16(spre_src + (size_t)tt2 * 1024, &spre[(t + 2) % 3][w * 512]);
    }
    __builtin_amdgcn_sched_barrier(0);
    // op3: sidx for t+3
    {
      int t3 = (t + 3 < T_N) ? (t + 3) : (T_N - 1);
      glds4(sidx_base + (size_t)t3 * sidx_stride, &sidxl[(t + 3) & 3][0]);
    }
    __builtin_amdgcn_sched_barrier(0);

    // ---- MFMA: msg = s @ Uh (wave's 96-col slice) ----
    f32x4 acc[6];
    #pragma unroll
    for (int i = 0; i < 6; ++i) acc[i] = (f32x4){0.f, 0.f, 0.f, 0.f};
    #pragma unroll
    for (int kk = 0; kk < 8; ++kk) {
      f16x8 a = *(const f16x8*)(s16 + l15 * S16P + kk * 32 + lhi * 8);
      #pragma unroll
      for (int nt = 0; nt < 6; ++nt)
        acc[nt] = __builtin_amdgcn_mfma_f32_16x16x32_f16(a, uh[kk * 6 + nt], acc[nt], 0, 0, 0);
    }

    // ---- wait pre[t], update ----
    asm volatile("s_waitcnt vmcnt(7)" ::: "memory");
    __builtin_amdgcn_sched_barrier(0);
    {
      const int* six = &sidxl[t & 3][lhi * 8];
      int c0 = six[0], c1 = six[1], c2 = six[2], c3 = six[3];
      int mfl = six[7];
      float cnt  = (float)(c0 + c1 + c2 + c3);
      float rcnt = __builtin_amdgcn_rcpf(fmaxf(cnt, 1.f));
      #pragma unroll
      for (int ub2 = 0; ub2 < 2; ++ub2) {
        int u = w * 32 + ub2 * 16 + l15;
        f16x4 p = *(const f16x4*)&spre[t % 3][lhi * 1024 + u * 4];
        float mr = acc[ub2 * 3 + 0][0];
        float mz = acc[ub2 * 3 + 1][0];
        float mh = acc[ub2 * 3 + 2][0];
        float tr = (float)p.x + mr;
        float tz = (float)p.y + mz;
        float hx = (float)p.z;
        float he = (float)p.w;
        float rg = __builtin_amdgcn_rcpf(1.f + __expf(-tr));
        float zg = __builtin_amdgcn_rcpf(1.f + __expf(-tz));
        float aa = hx + rg * (mh + he);
        float hc = 2.f * __builtin_amdgcn_rcpf(1.f + __expf(-2.f * aa)) - 1.f;
        float sv = (float)s16[(lhi * 4) * S16P + u];
        float hb = sv * rcnt;
        float hn = zg * hb + (1.f - zg) * hc;
        float hp_ = (float)hring[(t + 1) & 1][lhi * 256 + u];
        float ho = mfl ? hn : hp_;
        hring[t & 1][lhi * 256 + u] = (f16)ho;
      }
    }
    asm volatile("s_waitcnt lgkmcnt(0)" ::: "memory");
    __builtin_amdgcn_s_barrier();
    __builtin_amdgcn_sched_barrier(0);
  }

  // ---- epilogue: out = m[T-1] ? h[T-1] : 0 ----
  if (tid < 128) {
    const int rr = tid >> 5, uo = (tid & 31) * 8;
    int m = sidxl[(T_N - 1) & 3][rr * 8 + 7];
    f16x8 h8 = *(const f16x8*)&hring[(T_N - 1) & 1][rr * 256 + uo];
    f32x4 o0, o1;
    #pragma unroll
    for (int j = 0; j < 4; ++j) {
      o0[j] = m ? (float)h8[j]     : 0.f;
      o1[j] = m ? (float)h8[j + 4] : 0.f;
    }
    *(f32x4*)(out + (size_t)(b0 + rr) * 256 + uo)     = o0;
    *(f32x4*)(out + (size_t)(b0 + rr) * 256 + uo + 4) = o1;
  }
}

extern "C" void kernel_launch(void* const* d_in, const int* in_sizes, int n_in,
                              void* d_out, int out_size, void* d_ws, size_t ws_size,
                              hipStream_t stream)
{
  const float* inputs = (const float*)d_in[0];
  const int*   deps   = (const int*)d_in[2];
  const int*   et     = (const int*)d_in[3];
  const int*   msk    = (const int*)d_in[4];
  const int*   cmk    = (const int*)d_in[5];
  const float* Wx     = (const float*)d_in[6];
  const float* Uh     = (const float*)d_in[7];
  const float* Ve     = (const float*)d_in[8];
  const float* bb     = (const float*)d_in[9];
  const float* emb    = (const float*)d_in[10];
  float* out = (float*)d_out;

  char* ws = (char*)d_ws;
  f16*   A     = (f16*)ws;                     // 128 MB (dead after GEMM)
  f16*   H16   = (f16*)ws;                     // 64.125 MB alias of A (T+1 rows)
  f16*   pre   = (f16*)(ws + 134217728);       // 256 MB
  f16*   WcatT = (f16*)(ws + 402653184);       // 1 MB
  float* bias  = (float*)(ws + 403701760);     // 4 KB
  f16*   UhF   = (f16*)(ws + 403705856);       // 384 KB

  int prep_n = NC * KC + U_N * G3 + NC;
  k_prep<<<dim3((prep_n + 255) / 256), dim3(256), 0, stream>>>(Wx, Uh, Ve, bb, WcatT, bias, UhF);
  k_build_a<<<dim3(M_N / 4), dim3(256), 0, stream>>>(inputs, et, cmk, emb, A);
  k_gemm<<<dim3((M_N / 128) * (NC / 128)), dim3(256), 0, stream>>>(A, WcatT, bias, pre);
  k_scan4<<<dim3(B_N / 4), dim3(512), 0, stream>>>(pre, UhF, deps, cmk, msk, H16, out);
}

// Round 6
// 507.330 us; speedup vs baseline: 4.9028x; 1.1424x over previous
//
#include <hip/hip_runtime.h>
#include <hip/hip_bf16.h>
#include <stdint.h>

typedef _Float16 f16;
typedef _Float16 f16x8 __attribute__((ext_vector_type(8)));
typedef _Float16 f16x4 __attribute__((ext_vector_type(4)));
typedef float    f32x4 __attribute__((ext_vector_type(4)));

#define B_N 1024
#define T_N 128
#define U_N 256
#define G3  768    // 3U
#define NC  1024   // pre columns, permuted: col' = u*4 + part, part in {r,z,xh,eh}
#define KC  512    // concat K: [inputs | em_sum]
#define M_N (B_N * T_N)
#define S16P 264   // f16 LDS row stride

__device__ __forceinline__ void glds16(const void* g, void* l) {
  __builtin_amdgcn_global_load_lds((const __attribute__((address_space(1))) unsigned int*)g,
                                   (__attribute__((address_space(3))) unsigned int*)l, 16, 0, 0);
}
__device__ __forceinline__ void glds4(const void* g, void* l) {
  __builtin_amdgcn_global_load_lds((const __attribute__((address_space(1))) unsigned int*)g,
                                   (__attribute__((address_space(3))) unsigned int*)l, 4, 0, 0);
}

// ---------------- prep: B2 (f16, tile-major pre-swizzled), bias' (f32 1024), UhF ----------------
// B2 flat: (nt8*16 + kt)*4096 + r*32 + slot*8 + e  holds BT_orig[nt8*128+r][kt*32 + ((slot^swz(r))&3)*8 + e]
// swz(r) = ((r>>2)^r)&3
__global__ void k_prep(const float* __restrict__ Wx, const float* __restrict__ Uh,
                       const float* __restrict__ Ve, const float* __restrict__ bsrc,
                       f16* __restrict__ B2, float* __restrict__ bias, f16* __restrict__ UhF)
{
  int idx = blockIdx.x * 256 + threadIdx.x;
  if (idx < NC * KC) {
    int e = idx & 7, slot = (idx >> 3) & 3, r = (idx >> 5) & 127;
    int kt = (idx >> 12) & 15, nt8 = idx >> 16;
    int swz = ((r >> 2) ^ r) & 3;
    int np = nt8 * 128 + r;
    int k  = kt * 32 + ((slot ^ swz) & 3) * 8 + e;
    int u = np >> 2, part = np & 3;
    float v;
    if (part == 0)      v = (k < 256) ? Wx[k * G3 + u]         : Ve[(k - 256) * G3 + u];
    else if (part == 1) v = (k < 256) ? Wx[k * G3 + 256 + u]   : Ve[(k - 256) * G3 + 256 + u];
    else if (part == 2) v = (k < 256) ? Wx[k * G3 + 512 + u]   : 0.f;
    else                v = (k < 256) ? 0.f                    : Ve[(k - 256) * G3 + 512 + u];
    B2[idx] = (f16)v;
    return;
  }
  int i2 = idx - NC * KC;
  if (i2 < U_N * G3) {
    int j = i2 & 7, lane = (i2 >> 3) & 63, fn = i2 >> 9;   // fn = (w*8+kk)*6+nt
    int nt = fn % 6, kkw = fn / 6;
    int kk = kkw & 7, w = kkw >> 3;
    int k = kk * 32 + (lane >> 4) * 8 + j;
    int npp = w * 96 + nt * 16 + (lane & 15);
    int q = npp >> 4;
    int u = (q / 3) * 16 + (npp & 15), gate = q % 3;
    UhF[i2] = (f16)Uh[k * G3 + gate * 256 + u];
    return;
  }
  int i3 = i2 - U_N * G3;
  if (i3 < NC) {
    int u = i3 >> 2, part = i3 & 3;
    bias[i3] = (part < 3) ? bsrc[part * 256 + u] : 0.f;
  }
}

// ---------------- build A2 (f16, tile-major pre-swizzled) ----------------
// idx = ((b*16 + kt)*128 + t)*4 + slot ; thread writes 8 f16 at A2[idx*8]
// value = A_orig[b*128+t][kt*32 + ((slot^swz(t))&3)*8 + e]
__global__ __launch_bounds__(256) void k_build_a2(const float* __restrict__ inp, const int* __restrict__ et,
                           const int* __restrict__ cmk, const float* __restrict__ emb,
                           f16* __restrict__ A2)
{
  int idx = blockIdx.x * 256 + threadIdx.x;        // 8,388,608 total
  int slot = idx & 3, t = (idx >> 2) & 127, kt = (idx >> 9) & 15, b = idx >> 13;
  int swz = ((t >> 2) ^ t) & 3;
  int k0 = kt * 32 + ((slot ^ swz) & 3) * 8;
  int m = b * 128 + t;
  f16x8 v;
  if (k0 < 256) {
    const float* s = inp + (size_t)m * 256 + k0;
    #pragma unroll
    for (int j = 0; j < 8; ++j) v[j] = (f16)s[j];
  } else {
    int c = k0 - 256;
    const int* e  = et  + (size_t)m * 4;
    const int* cm = cmk + (size_t)m * 4;
    float a[8] = {0,0,0,0,0,0,0,0};
    #pragma unroll
    for (int r = 0; r < 4; ++r)
      if (cm[r]) {
        const float* es = emb + e[r] * U_N + c;
        #pragma unroll
        for (int j = 0; j < 8; ++j) a[j] += es[j];
      }
    #pragma unroll
    for (int j = 0; j < 8; ++j) v[j] = (f16)a[j];
  }
  *(f16x8*)(A2 + (size_t)idx * 8) = v;
}

// ---------------- GEMM: pre[M][1024] (f16) = A[M][512] @ B^T + bias' ----------------
// 128x128 tile, BK=32, triple-buffered global_load_lds staging, counted vmcnt.
// Tile stride: 128 rows x 32 k = 4096 f16 ELEMENTS per (tile, K-step).
__global__ __launch_bounds__(256) void k_gemm2(const f16* __restrict__ A2,
                                               const f16* __restrict__ B2,
                                               const float* __restrict__ bias,
                                               f16* __restrict__ C)
{
  __shared__ __align__(16) f16 sbuf[3][2][4096];   // 49152 B
  const int tid  = threadIdx.x;
  const int lane = tid & 63, wv = tid >> 6;
  const int wm = wv >> 1, wn = wv & 1;
  const int l15 = lane & 15, lhi = lane >> 4;
  const int wg = (blockIdx.x & 7) * 1024 + (blockIdx.x >> 3);
  const int mt = wg >> 3, nt = wg & 7;
  const int m0 = mt * 128, n0 = nt * 128;

  const f16* gabase = A2 + (size_t)mt * 16 * 4096 + wv * 1024 + lane * 8;
  const f16* gbbase = B2 + (size_t)nt * 16 * 4096 + wv * 1024 + lane * 8;

  // stage K-step kt into buf: 4 glds16 per wave (2 A-insts, 2 B-insts)
  #define STAGE(kt_, buf_) do {                                             \
    int kk_ = (kt_);                                                        \
    glds16(gabase + (size_t)kk_ * 4096,       &sbuf[buf_][0][wv * 1024]);   \
    glds16(gabase + (size_t)kk_ * 4096 + 512, &sbuf[buf_][0][wv * 1024 + 512]); \
    glds16(gbbase + (size_t)kk_ * 4096,       &sbuf[buf_][1][wv * 1024]);   \
    glds16(gbbase + (size_t)kk_ * 4096 + 512, &sbuf[buf_][1][wv * 1024 + 512]); \
  } while (0)

  f32x4 acc[4][4] = {};

  STAGE(0, 0);
  STAGE(1, 1);
  __builtin_amdgcn_sched_barrier(0);

  // precompute read offsets (swizzle baked: slot = lhi ^ swz(row))
  int aoff[4], boff[4];
  #pragma unroll
  for (int i = 0; i < 4; ++i) {
    int ar = wm * 64 + i * 16 + l15;
    aoff[i] = ar * 32 + ((lhi ^ ((ar >> 2) ^ ar)) & 3) * 8;
    int br = wn * 64 + i * 16 + l15;
    boff[i] = br * 32 + ((lhi ^ ((br >> 2) ^ br)) & 3) * 8;
  }

  for (int t = 0; t < 16; ++t) {
    const int buf  = t % 3;
    const int bufp = (t + 2) % 3;
    STAGE((t + 2 < 16) ? (t + 2) : 15, bufp);
    __builtin_amdgcn_sched_barrier(0);
    asm volatile("s_waitcnt vmcnt(8)" ::: "memory");
    __builtin_amdgcn_sched_barrier(0);
    __builtin_amdgcn_s_barrier();
    __builtin_amdgcn_sched_barrier(0);

    const f16* sA = &sbuf[buf][0][0];
    const f16* sB = &sbuf[buf][1][0];
    f16x8 af[4], bf[4];
    #pragma unroll
    for (int i = 0; i < 4; ++i) {
      af[i] = *(const f16x8*)(sA + aoff[i]);
      bf[i] = *(const f16x8*)(sB + boff[i]);
    }
    #pragma unroll
    for (int i = 0; i < 4; ++i)
      #pragma unroll
      for (int j = 0; j < 4; ++j)
        acc[i][j] = __builtin_amdgcn_mfma_f32_16x16x32_f16(af[i], bf[j], acc[i][j], 0, 0, 0);

    asm volatile("s_waitcnt lgkmcnt(0)" ::: "memory");
    __builtin_amdgcn_s_barrier();
    __builtin_amdgcn_sched_barrier(0);
  }

  // bias loads, then full drain (pending clamped prefetches still write sbuf)
  float bv[4];
  #pragma unroll
  for (int j = 0; j < 4; ++j) bv[j] = bias[n0 + wn * 64 + j * 16 + l15];
  asm volatile("s_waitcnt vmcnt(0)" ::: "memory");
  __builtin_amdgcn_sched_barrier(0);
  __builtin_amdgcn_s_barrier();

  // epilogue via LDS: [128][132] f16 (33792 B, aliases sbuf)
  f16* ep = &sbuf[0][0][0];
  #pragma unroll
  for (int i = 0; i < 4; ++i)
    #pragma unroll
    for (int j = 0; j < 4; ++j)
      #pragma unroll
      for (int r = 0; r < 4; ++r)
        ep[(wm * 64 + i * 16 + lhi * 4 + r) * 132 + wn * 64 + j * 16 + l15] =
            (f16)(acc[i][j][r] + bv[j]);
  __syncthreads();

  #pragma unroll
  for (int it = 0; it < 8; ++it) {
    int row = it * 16 + (tid >> 4), chunk = tid & 15;
    *(f16x8*)(C + (size_t)(m0 + row) * 1024 + n0 + chunk * 8) =
        *(const f16x8*)(ep + row * 132 + chunk * 8);
  }
  #undef STAGE
}

// ---------------- scan: 256 blocks x 512 threads, 4 batch rows per block (unchanged) ----------------
__global__ __launch_bounds__(512, 2) void k_scan4(
    const f16* __restrict__ pre,   // [B*T][1024], col' = u*4 + {r,z,xh,eh}
    const f16* __restrict__ UhF,
    const int* __restrict__ dep,   // [B][T][3]
    const int* __restrict__ cmk,   // [B][T][4]
    const int* __restrict__ msk,   // [B][T]
    f16* __restrict__ H16,         // [T+1][B][256] f16 (row T = scratch)
    float* __restrict__ out)       // [B][256]
{
  __shared__ __align__(16) f16 s16[16 * S16P];
  __shared__ __align__(16) f16 hring[2][1024];
  __shared__ __align__(16) f16 dbuf[2][3072];
  __shared__ __align__(16) f16 spre[3][4096];
  __shared__ __align__(16) int sidxl[4][64];
  __shared__ __align__(16) int dpad[64];

  const int tid  = threadIdx.x;
  const int lane = tid & 63, w = tid >> 6;
  const int l15  = lane & 15, lhi = lane >> 4;
  const int b0   = blockIdx.x * 4;

  f16x8 uh[48];
  {
    const f16* ub = UhF + ((size_t)w * 48 * 64 + lane) * 8;
    #pragma unroll
    for (int i = 0; i < 48; ++i) uh[i] = *(const f16x8*)(ub + i * 512);
  }

  ((int*)hring)[tid]       = 0;
  ((int*)hring)[tid + 512] = 0;

  if (tid < 96) {
    int tt = tid >> 5, ll2 = tid & 31, rr = ll2 >> 3, f = ll2 & 7;
    size_t b = b0 + rr;
    int v;
    if (f < 4)      v = cmk[(b * T_N + tt) * 4 + f];
    else if (f < 7) v = dep[(b * T_N + tt) * 3 + (f - 4)];
    else            v = msk[b * T_N + tt];
    sidxl[tt][rr * 8 + f] = v;
  }
  __syncthreads();

  const f16* spre_src = pre + ((size_t)(b0 + (w >> 1)) * T_N) * 1024 + (w & 1) * 512 + lane * 8;
  const int  ll = lane & 31;
  const int  srr = ll >> 3, sf = ll & 7;
  const size_t sb = b0 + srr;
  const int* sidx_base;
  int sidx_stride;
  if (sf < 4)      { sidx_base = cmk + sb * T_N * 4 + sf;       sidx_stride = 4; }
  else if (sf < 7) { sidx_base = dep + sb * T_N * 3 + (sf - 4); sidx_stride = 3; }
  else             { sidx_base = msk + sb * T_N;                sidx_stride = 1; }
  const int dq  = 2 * w + (lane >> 5);
  const int drr = dq / 3, drm = dq - drr * 3;
  const f16* dsrc_base = H16 + (size_t)(b0 + drr) * 256 + (lane & 31) * 8;
  const int strr = ((w - 6) * 64 + lane) >> 5;
  const int stuo = (((w - 6) * 64 + lane) & 31) * 8;

  #pragma unroll
  for (int pr = 0; pr < 2; ++pr)
    glds16(spre_src + (size_t)pr * 1024, &spre[pr][w * 512]);
  #pragma unroll
  for (int i = 0; i < 3; ++i)
    glds4(msk, &dpad[0]);

  for (int t = 0; t < T_N; ++t) {
    asm volatile("s_waitcnt vmcnt(2)" ::: "memory");
    __builtin_amdgcn_sched_barrier(0);

    if (tid < 128) {
      const int rr = tid >> 5, uo = (tid & 31) * 8;
      const int* six = &sidxl[t & 3][rr * 8];
      int cm0 = six[0];
      int cms0 = six[1], cms1 = six[2], cms2 = six[3];
      int dd0 = six[4],  dd1 = six[5],  dd2 = six[6];
      f16x8 hprev = *(const f16x8*)&hring[(t + 1) & 1][rr * 256 + uo];
      f16x8 hold  = *(const f16x8*)&hring[t & 1][rr * 256 + uo];
      f32x4 a0 = {0.f,0.f,0.f,0.f}, a1 = {0.f,0.f,0.f,0.f};
      if (cm0) {
        #pragma unroll
        for (int j = 0; j < 4; ++j) { a0[j] += (float)hprev[j]; a1[j] += (float)hprev[j + 4]; }
      }
      int cma[3] = {cms0, cms1, cms2};
      int dda[3] = {dd0, dd1, dd2};
      #pragma unroll
      for (int r = 0; r < 3; ++r) {
        f16x8 dv = *(const f16x8*)&dbuf[t & 1][(rr * 3 + r) * 256 + uo];
        int d = dda[r];
        f16x8 src = (d == t - 1) ? hprev : ((d == t - 2) ? hold : dv);
        if (cma[r] && (d < t)) {
          #pragma unroll
          for (int j = 0; j < 4; ++j) { a0[j] += (float)src[j]; a1[j] += (float)src[j + 4]; }
        }
      }
      f16x8 s8;
      #pragma unroll
      for (int j = 0; j < 4; ++j) { s8[j] = (f16)a0[j]; s8[j + 4] = (f16)a1[j]; }
      *(f16x8*)&s16[(rr * 4) * S16P + uo] = s8;
    }
    asm volatile("s_waitcnt lgkmcnt(0)" ::: "memory");
    __builtin_amdgcn_s_barrier();
    __builtin_amdgcn_sched_barrier(0);

    if (w < 6) {
      int d = sidxl[(t + 1) & 3][drr * 8 + 4 + drm];
      glds16(dsrc_base + (size_t)d * (B_N * 256), &dbuf[(t + 1) & 1][w * 512]);
    } else {
      f16x8 hv = *(const f16x8*)&hring[(t + 1) & 1][strr * 256 + stuo];
      int tt = (t == 0) ? T_N : (t - 1);
      *(f16x8*)(H16 + ((size_t)tt * B_N + b0 + strr) * 256 + stuo) = hv;
    }
    __builtin_amdgcn_sched_barrier(0);
    {
      int tt2 = (t + 2 < T_N) ? (t + 2) : (T_N - 1);
      glds16(spre_src + (size_t)tt2 * 1024, &spre[(t + 2) % 3][w * 512]);
    }
    __builtin_amdgcn_sched_barrier(0);
    {
      int t3 = (t + 3 < T_N) ? (t + 3) : (T_N - 1);
      glds4(sidx_base + (size_t)t3 * sidx_stride, &sidxl[(t + 3) & 3][0]);
    }
    __builtin_amdgcn_sched_barrier(0);

    f32x4 acc[6];
    #pragma unroll
    for (int i = 0; i < 6; ++i) acc[i] = (f32x4){0.f, 0.f, 0.f, 0.f};
    #pragma unroll
    for (int kk = 0; kk < 8; ++kk) {
      f16x8 a = *(const f16x8*)(s16 + l15 * S16P + kk * 32 + lhi * 8);
      #pragma unroll
      for (int nt = 0; nt < 6; ++nt)
        acc[nt] = __builtin_amdgcn_mfma_f32_16x16x32_f16(a, uh[kk * 6 + nt], acc[nt], 0, 0, 0);
    }

    asm volatile("s_waitcnt vmcnt(7)" ::: "memory");
    __builtin_amdgcn_sched_barrier(0);
    {
      const int* six = &sidxl[t & 3][lhi * 8];
      int c0 = six[0], c1 = six[1], c2 = six[2], c3 = six[3];
      int mfl = six[7];
      float cnt  = (float)(c0 + c1 + c2 + c3);
      float rcnt = __builtin_amdgcn_rcpf(fmaxf(cnt, 1.f));
      #pragma unroll
      for (int ub2 = 0; ub2 < 2; ++ub2) {
        int u = w * 32 + ub2 * 16 + l15;
        f16x4 p = *(const f16x4*)&spre[t % 3][lhi * 1024 + u * 4];
        float mr = acc[ub2 * 3 + 0][0];
        float mz = acc[ub2 * 3 + 1][0];
        float mh = acc[ub2 * 3 + 2][0];
        float tr = (float)p.x + mr;
        float tz = (float)p.y + mz;
        float hx = (float)p.z;
        float he = (float)p.w;
        float rg = __builtin_amdgcn_rcpf(1.f + __expf(-tr));
        float zg = __builtin_amdgcn_rcpf(1.f + __expf(-tz));
        float aa = hx + rg * (mh + he);
        float hc = 2.f * __builtin_amdgcn_rcpf(1.f + __expf(-2.f * aa)) - 1.f;
        float sv = (float)s16[(lhi * 4) * S16P + u];
        float hb = sv * rcnt;
        float hn = zg * hb + (1.f - zg) * hc;
        float hp_ = (float)hring[(t + 1) & 1][lhi * 256 + u];
        float ho = mfl ? hn : hp_;
        hring[t & 1][lhi * 256 + u] = (f16)ho;
      }
    }
    asm volatile("s_waitcnt lgkmcnt(0)" ::: "memory");
    __builtin_amdgcn_s_barrier();
    __builtin_amdgcn_sched_barrier(0);
  }

  if (tid < 128) {
    const int rr = tid >> 5, uo = (tid & 31) * 8;
    int m = sidxl[(T_N - 1) & 3][rr * 8 + 7];
    f16x8 h8 = *(const f16x8*)&hring[(T_N - 1) & 1][rr * 256 + uo];
    f32x4 o0, o1;
    #pragma unroll
    for (int j = 0; j < 4; ++j) {
      o0[j] = m ? (float)h8[j]     : 0.f;
      o1[j] = m ? (float)h8[j + 4] : 0.f;
    }
    *(f32x4*)(out + (size_t)(b0 + rr) * 256 + uo)     = o0;
    *(f32x4*)(out + (size_t)(b0 + rr) * 256 + uo + 4) = o1;
  }
}

extern "C" void kernel_launch(void* const* d_in, const int* in_sizes, int n_in,
                              void* d_out, int out_size, void* d_ws, size_t ws_size,
                              hipStream_t stream)
{
  const float* inputs = (const float*)d_in[0];
  const int*   deps   = (const int*)d_in[2];
  const int*   et     = (const int*)d_in[3];
  const int*   msk    = (const int*)d_in[4];
  const int*   cmk    = (const int*)d_in[5];
  const float* Wx     = (const float*)d_in[6];
  const float* Uh     = (const float*)d_in[7];
  const float* Ve     = (const float*)d_in[8];
  const float* bb     = (const float*)d_in[9];
  const float* emb    = (const float*)d_in[10];
  float* out = (float*)d_out;

  char* ws = (char*)d_ws;
  f16*   A2    = (f16*)ws;                     // 128 MB (dead after GEMM)
  f16*   H16   = (f16*)ws;                     // 64.125 MB alias of A2 (T+1 rows)
  f16*   pre   = (f16*)(ws + 134217728);       // 256 MB
  f16*   B2    = (f16*)(ws + 402653184);       // 1 MB
  float* bias  = (float*)(ws + 403701760);     // 4 KB
  f16*   UhF   = (f16*)(ws + 403705856);       // 384 KB

  int prep_n = NC * KC + U_N * G3 + NC;
  k_prep<<<dim3((prep_n + 255) / 256), dim3(256), 0, stream>>>(Wx, Uh, Ve, bb, B2, bias, UhF);
  k_build_a2<<<dim3(M_N * 64 / 256), dim3(256), 0, stream>>>(inputs, et, cmk, emb, A2);
  k_gemm2<<<dim3((M_N / 128) * (NC / 128)), dim3(256), 0, stream>>>(A2, B2, bias, pre);
  k_scan4<<<dim3(B_N / 4), dim3(512), 0, stream>>>(pre, UhF, deps, cmk, msk, H16, out);
}